// Round 1
// 1623.203 us; speedup vs baseline: 1.4612x; 1.4612x over previous
//
#include <hip/hip_runtime.h>
#include <math.h>

#define Bb 64
#define Ll 512
#define Dd 512
#define Ff 2048
#define Ee 8

typedef _Float16 half_t;
typedef _Float16 half8 __attribute__((ext_vector_type(8)));
typedef float f32x4 __attribute__((ext_vector_type(4)));

// ws layout (halves): W1t [E][F][D] at 0 ; W2t [E][D][F] at W2T_OFF
#define W2T_OFF ((size_t)Ee * Dd * Ff)

__device__ __forceinline__ void dma16(const half_t* g, half_t* l) {
    // global -> LDS direct DMA, 16B per lane; LDS dst = uniform base + lane*16
    __builtin_amdgcn_global_load_lds((const __attribute__((address_space(1))) void*)g,
                                     (__attribute__((address_space(3))) void*)l, 16, 0, 0);
}
__device__ __forceinline__ void dma16f(const float* g, float* l) {
    __builtin_amdgcn_global_load_lds((const __attribute__((address_space(1))) void*)g,
                                     (__attribute__((address_space(3))) void*)l, 16, 0, 0);
}

// Counted-vmcnt barrier discipline (T4-lite): never drain vmcnt(0) mid-stream.
// "memory" clobber = compile-time fence so dma issues / ds ops cannot cross.
#define VWAIT(n)  asm volatile("s_waitcnt vmcnt(" #n ")" ::: "memory")
#define VLWAIT(n) asm volatile("s_waitcnt vmcnt(" #n ") lgkmcnt(0)" ::: "memory")
#define BAR() do { __builtin_amdgcn_s_barrier();                 \
                   asm volatile("" ::: "memory");                \
                   __builtin_amdgcn_sched_barrier(0); } while (0)

// ---------------- prep: fp32 [R][C] -> fp16 [C][R] transpose ----------------
__global__ __launch_bounds__(256)
void prep_transpose(const float* __restrict__ w1, const float* __restrict__ w2,
                    half_t* __restrict__ ws)
{
    __shared__ half_t T[64 * 72];
    int bid = blockIdx.x;
    const float* src; half_t* dst; int R, C, r0, c0;
    if (bid < 2048) {            // W1 per e: R=512(d), C=2048(f): 8 x 32 tiles
        int e = bid >> 8, t = bid & 255;
        r0 = (t >> 5) * 64; c0 = (t & 31) * 64;
        src = w1 + (size_t)e * Dd * Ff;
        dst = ws + (size_t)e * Ff * Dd;
        R = Dd; C = Ff;
    } else {                     // W2 per e: R=2048(f), C=512(d): 32 x 8 tiles
        bid -= 2048;
        int e = bid >> 8, t = bid & 255;
        r0 = (t >> 3) * 64; c0 = (t & 7) * 64;
        src = w2 + (size_t)e * Ff * Dd;
        dst = ws + W2T_OFF + (size_t)e * Dd * Ff;
        R = Ff; C = Dd;
    }
    const int cx = threadIdx.x & 63, ry = threadIdx.x >> 6;
    #pragma unroll
    for (int j = 0; j < 16; ++j) {
        int r = ry * 16 + j;
        T[cx * 72 + r] = (half_t)src[(size_t)(r0 + r) * C + c0 + cx];
    }
    __syncthreads();
    const int rx = threadIdx.x & 7;
    #pragma unroll
    for (int it = 0; it < 2; ++it) {
        int cr = (threadIdx.x >> 3) + it * 32;
        *(half8*)&dst[(size_t)(c0 + cr) * R + r0 + rx * 8] = *(half8*)&T[cr * 72 + rx * 8];
    }
}

// ---------------- main fused MoE ----------------
// Block = (b, 64-token tile), 512 thr / 8 waves, 1 block/CU (LDS 112.5KB).
// 3-buffer weight pipeline, prefetch distance 2, counted vmcnt across raw
// s_barriers: per-wave steady-state waits are vmcnt(4) (vmcnt(5) at nc2 where
// the 1-load bias DMA joins the stream). LPT balance: b = rank-ordered by
// active-expert count so heavy rows dispatch first.
__global__ __launch_bounds__(512, 2)
void moe_main(const float* __restrict__ x, const float* __restrict__ logits,
              const int* __restrict__ masks, const half_t* __restrict__ ws,
              const float* __restrict__ b1, const float* __restrict__ b2,
              float* __restrict__ out)
{
    __shared__ half_t Wbuf[3][128 * 128];   // 3 x 32KB rotating weight tiles
    __shared__ half_t Hs[64 * 128];         // 16KB hidden tile
    __shared__ float  Bs[128];              // b1 chunk for current fci

    const int tid  = threadIdx.x;
    const int wv   = tid >> 6;
    const int lane = tid & 63;
    const int nl   = lane & 15;
    const int q    = lane >> 4;
    const int mt   = wv >> 1;     // m-tile (tokens), both phases
    const int nh   = wv & 1;      // n-split within pair
    const int rl   = lane >> 4;   // DMA row-within-4
    const int pcl  = lane & 15;   // DMA 16B slot

    const int bid = blockIdx.x;

    // ---- LPT rank: b = (bid>>3)-th heaviest batch row; tiles spread over XCDs
    int b;
    {
        int cj = 0;
        #pragma unroll
        for (int e2 = 0; e2 < Ee; ++e2) cj += (masks[lane * Ee + e2] == 1);
        int rj = 0;
        for (int k = 0; k < Bb; ++k) {
            const int ck = __shfl(cj, k);
            rj += (ck > cj) || (ck == cj && k < lane);
        }
        const unsigned long long mword = __ballot(rj == (bid >> 3));
        b = (int)__builtin_ctzll(mword);
    }
    const int l0 = (bid & 7) * 64;

    // ---- gates: uniform softmax math; lane holds gate[lane&7] ----
    float mx = -1e30f;
    #pragma unroll
    for (int e = 0; e < Ee; ++e) mx = fmaxf(mx, logits[b * Ee + e]);
    float s = 0.f, gs = 0.f;
    unsigned am = 0u;
    #pragma unroll
    for (int e = 0; e < Ee; ++e) {
        const float ex = expf(logits[b * Ee + e] - mx);
        s += ex;
        if (masks[b * Ee + e] == 1) { gs += ex; am |= (1u << e); }
    }
    const int el = lane & 7;
    const float myg = ((am >> el) & 1u)
        ? expf(logits[b * Ee + el] - mx) / (gs + 1e-9f * s) : 0.f;
    float ge[Ee];                    // static-indexed copy for final epilogue
    #pragma unroll
    for (int e = 0; e < Ee; ++e) ge[e] = __shfl(myg, e);

    // ---- persistent X A-fragments: A[m=nl][k=q*8+j], 16 ksteps over K=512 ----
    half8 afrag[16];
    {
        const float* xrow = x + (size_t)(b * Ll + l0 + mt * 16 + nl) * Dd;
        #pragma unroll
        for (int ks = 0; ks < 16; ++ks) {
            const int c0 = ks * 32 + q * 8;
            const f32x4 u0 = *(const f32x4*)(xrow + c0);
            const f32x4 u1 = *(const f32x4*)(xrow + c0 + 4);
            half8 a;
            a[0]=(half_t)u0[0]; a[1]=(half_t)u0[1]; a[2]=(half_t)u0[2]; a[3]=(half_t)u0[3];
            a[4]=(half_t)u1[0]; a[5]=(half_t)u1[1]; a[6]=(half_t)u1[2]; a[7]=(half_t)u1[3];
            afrag[ks] = a;
        }
    }

    f32x4 oacc[16];
    #pragma unroll
    for (int i = 0; i < 16; ++i) oacc[i] = (f32x4){0.f, 0.f, 0.f, 0.f};

    auto stageT = [&](const half_t* src, int ld, half_t* dst) {
        #pragma unroll
        for (int ss = 0; ss < 4; ++ss) {
            const int row = wv * 16 + ss * 4 + rl;
            const int c = pcl ^ (row & 15);
            dma16(src + (size_t)row * ld + c * 8, dst + (wv * 16 + ss * 4) * 128);
        }
    };
    auto computeA = [&](const half8* af, const half_t* Wb, f32x4* hc) {
        #pragma unroll
        for (int ks = 0; ks < 4; ++ks) {
            const half8 a = af[ks];
            #pragma unroll
            for (int nf = 0; nf < 4; ++nf) {
                const int row = nh * 64 + nf * 16 + nl;
                const half8 bf = *(const half8*)&Wb[row * 128 + (((ks * 4 + q) ^ nl) * 8)];
                hc[nf] = __builtin_amdgcn_mfma_f32_16x16x32_f16(a, bf, hc[nf], 0, 0, 0);
            }
        }
    };
    auto computeB = [&](const half8* ha, const half_t* Wb, f32x4* oc) {
        #pragma unroll
        for (int ks = 0; ks < 4; ++ks) {
            #pragma unroll
            for (int t = 0; t < 4; ++t) {
                const int lr = t * 32 + nh * 16 + nl;
                const half8 bf = *(const half8*)&Wb[lr * 128 + (((ks * 4 + q) ^ nl) * 8)];
                oc[t] = __builtin_amdgcn_mfma_f32_16x16x32_f16(ha[ks], bf, oc[t], 0, 0, 0);
            }
        }
    };

    int cur = 0;
    unsigned rem = am;
    if (rem) {  // prime: A(kc0)[4] + bias[1] + A(kc1)[4]; retire A0+bias, keep A1 in flight
        const int e0 = (int)__builtin_ctz(rem);
        const half_t* W1p = ws + (size_t)e0 * Ff * Dd;
        asm volatile("s_waitcnt vmcnt(0)" ::: "memory");   // drain afrag loads
        stageT(W1p,       Dd, Wbuf[0]);
        if (lane < 32) dma16f(b1 + (size_t)e0 * Ff + lane * 4, Bs);
        stageT(W1p + 128, Dd, Wbuf[1]);
        VWAIT(4);
        BAR();
    }

    while (rem) {
        const int e = (int)__builtin_ctz(rem); rem &= rem - 1u;
        const int en = rem ? (int)__builtin_ctz(rem) : -1;
        const float g = __shfl(myg, e);
        const half_t* W1te = ws + (size_t)e * Ff * Dd;            // [F][D]
        const half_t* W2te = ws + W2T_OFF + (size_t)e * Dd * Ff;  // [D][F]
        const half_t* W1nx = (en >= 0) ? ws + (size_t)en * Ff * Dd : W1te;
        const float*  b1nx = (en >= 0) ? b1 + (size_t)en * Ff : b1;

        #pragma unroll 1
        for (int fci = 0; fci < 16; ++fci) {
            const int f0 = fci * 128;
            const half_t* WA = W1te + (size_t)f0 * Dd;  // + kc*128 col offset
            const half_t* WB = W2te + f0;               // + nc*128*Ff row offset
            const bool hn = (fci < 15) || (en >= 0);
            const half_t* An = (fci < 15) ? (WA + (size_t)128 * Dd) : W1nx;
            const float*  bn = (fci < 15) ? (b1 + (size_t)e * Ff + f0 + 128) : b1nx;

            f32x4 hacc[4];
            #pragma unroll
            for (int i = 0; i < 4; ++i) hacc[i] = (f32x4){0.f, 0.f, 0.f, 0.f};

            // ---------- Phase A: 4 K-chunks of 128 ----------
            { half_t* Wp = Wbuf[cur ? cur - 1 : 2];            // kc0: prefetch A(kc2)
              stageT(WA + 2 * 128, Dd, Wp);
              computeA(&afrag[0], Wbuf[cur], hacc);
              VWAIT(4); BAR(); cur = (cur == 2) ? 0 : cur + 1; }
            { half_t* Wp = Wbuf[cur ? cur - 1 : 2];            // kc1: prefetch A(kc3)
              stageT(WA + 3 * 128, Dd, Wp);
              computeA(&afrag[4], Wbuf[cur], hacc);
              VWAIT(4); BAR(); cur = (cur == 2) ? 0 : cur + 1; }
            { half_t* Wp = Wbuf[cur ? cur - 1 : 2];            // kc2: prefetch B(nc0)
              stageT(WB, Ff, Wp);
              computeA(&afrag[8], Wbuf[cur], hacc);
              VWAIT(4); BAR(); cur = (cur == 2) ? 0 : cur + 1; }
            { half_t* Wp = Wbuf[cur ? cur - 1 : 2];            // kc3: prefetch B(nc1)
              stageT(WB + (size_t)128 * Ff, Ff, Wp);
              computeA(&afrag[12], Wbuf[cur], hacc);
              // epilogue A: bias + gelu + gate -> Hs (swizzled A-layout)
              #pragma unroll
              for (int nf = 0; nf < 4; ++nf) {
                  const int fl = nh * 64 + nf * 16 + nl;
                  const float bv = Bs[fl];
                  #pragma unroll
                  for (int r = 0; r < 4; ++r) {
                      const int m = mt * 16 + q * 4 + r;
                      const float v  = hacc[nf][r] + bv;
                      const float gl = 0.5f * v * (1.f + erff(v * 0.70710678118654752f));
                      const int blk = (fl >> 3) ^ (m & 15);
                      Hs[m * 128 + blk * 8 + (fl & 7)] = (half_t)(g * gl);
                  }
              }
              VLWAIT(4); BAR(); cur = (cur == 2) ? 0 : cur + 1; }

            // ---------- Phase B: 4 n-chunks of 128 ----------
            half8 ha[4];
            { half_t* Wp = Wbuf[cur ? cur - 1 : 2];            // nc0: prefetch B(nc2)
              #pragma unroll
              for (int ks = 0; ks < 4; ++ks)
                  ha[ks] = *(const half8*)&Hs[(mt * 16 + nl) * 128 + (((ks * 4 + q) ^ nl) * 8)];
              stageT(WB + (size_t)256 * Ff, Ff, Wp);
              computeB(ha, Wbuf[cur], &oacc[0]);
              VWAIT(4); BAR(); cur = (cur == 2) ? 0 : cur + 1; }
            { half_t* Wp = Wbuf[cur ? cur - 1 : 2];            // nc1: prefetch B(nc3)
              stageT(WB + (size_t)384 * Ff, Ff, Wp);
              computeB(ha, Wbuf[cur], &oacc[4]);
              VWAIT(4); BAR(); cur = (cur == 2) ? 0 : cur + 1; }
            { half_t* Wp = Wbuf[cur ? cur - 1 : 2];            // nc2: prefetch next A(kc0)+bias
              if (hn) {
                  stageT(An, Dd, Wp);
                  if (lane < 32) dma16f(bn + lane * 4, Bs);
              }
              computeB(ha, Wbuf[cur], &oacc[8]);
              if (hn) { VWAIT(5); } else { VWAIT(0); }
              BAR(); cur = (cur == 2) ? 0 : cur + 1; }
            { half_t* Wp = Wbuf[cur ? cur - 1 : 2];            // nc3: prefetch next A(kc1)
              if (hn) stageT(An + 128, Dd, Wp);
              computeB(ha, Wbuf[cur], &oacc[12]);
              if (hn) { VWAIT(4); } else { VWAIT(0); }
              BAR(); cur = (cur == 2) ? 0 : cur + 1; }
        }
    }

    // ---- epilogue: add sum_e gate[e]*b2[e,:] and store fp32 ----
    #pragma unroll
    for (int ncc = 0; ncc < 4; ++ncc) {
        #pragma unroll
        for (int t = 0; t < 4; ++t) {
            const int dcol = ncc * 128 + t * 32 + nh * 16 + nl;
            float bb = 0.f;
            #pragma unroll
            for (int e = 0; e < Ee; ++e) bb += ge[e] * b2[e * Dd + dcol];
            const f32x4 v = oacc[ncc * 4 + t];
            const size_t base = (size_t)(b * Ll + l0 + mt * 16 + q * 4) * Dd + dcol;
            out[base]          = v[0] + bb;
            out[base + Dd]     = v[1] + bb;
            out[base + 2 * Dd] = v[2] + bb;
            out[base + 3 * Dd] = v[3] + bb;
        }
    }
}

__global__ void moe_loss(const float* __restrict__ logits, const int* __restrict__ masks,
                         float* __restrict__ loss_out)
{
    const int b = threadIdx.x;   // 64 threads = 1 wave
    float lg[Ee];
    float mx = -1e30f;
    #pragma unroll
    for (int e = 0; e < Ee; ++e) { lg[e] = logits[b * Ee + e]; mx = fmaxf(mx, lg[e]); }
    float s = 0.f;
    #pragma unroll
    for (int e = 0; e < Ee; ++e) { float ex = expf(lg[e] - mx); s += ex; lg[e] = ex; }
    float rs = 0.f;
    #pragma unroll
    for (int e = 0; e < Ee; ++e) if (masks[b * Ee + e] == 1) rs += lg[e] / s;
    #pragma unroll
    for (int off = 32; off > 0; off >>= 1) rs += __shfl_down(rs, off);
    if (b == 0) {
        const float t = 1.f - rs / (float)Bb;
        loss_out[0] = t * t;
    }
}

extern "C" void kernel_launch(void* const* d_in, const int* in_sizes, int n_in,
                              void* d_out, int out_size, void* d_ws, size_t ws_size,
                              hipStream_t stream)
{
    const float* x      = (const float*)d_in[0];
    const float* logits = (const float*)d_in[1];
    const int*   masks  = (const int*)d_in[2];
    const float* w1     = (const float*)d_in[3];
    const float* b1     = (const float*)d_in[4];
    const float* w2     = (const float*)d_in[5];
    const float* b2     = (const float*)d_in[6];
    float* out = (float*)d_out;
    half_t* ws = (half_t*)d_ws;

    hipLaunchKernelGGL(prep_transpose, dim3(4096), dim3(256), 0, stream, w1, w2, ws);
    hipLaunchKernelGGL(moe_main, dim3(512), dim3(512), 0, stream,
                       x, logits, masks, ws, b1, b2, out);
    hipLaunchKernelGGL(moe_loss, dim3(1), dim3(64), 0, stream,
                       logits, masks, out + (size_t)Bb * Ll * Dd);
}